// Round 11
// baseline (192.371 us; speedup 1.0000x reference)
//
#include <hip/hip_runtime.h>
#include <hip/hip_bf16.h>
#include <math.h>

// Problem constants
#define TT    2048
#define HH    8
#define RDIM  32
#define BB    2

typedef float  f4  __attribute__((ext_vector_type(4)));
typedef int    i4  __attribute__((ext_vector_type(4)));
typedef uint   u2  __attribute__((ext_vector_type(2)));
typedef uint   u4  __attribute__((ext_vector_type(4)));
typedef short  s8v __attribute__((ext_vector_type(8)));   // 8 x bf16 bits (4 VGPR)

// round-to-nearest f32 -> bf16 bits
__device__ __forceinline__ uint rnd16(float x) {
    return (__float_as_uint(x) + 0x8000u) >> 16;
}

union v8cast { u4 u; s8v s; };

// ---------------------------------------------------------------------------
// Kernel 0: Wt prep — transpose (Wq|Wk)[1024][256+256] f32 -> Wt[512][1024]
// bf16 (Wt[n][k] = W[k][n]). LDS-tiled 64x64. 1 MB output, L2-resident.
// ---------------------------------------------------------------------------
__global__ __launch_bounds__(256) void wt_prep(
    const float* __restrict__ Wq,
    const float* __restrict__ Wk,
    ushort* __restrict__ Wt)
{
    __shared__ float T[64][68];
    const int k0 = blockIdx.x * 64;
    const int n0 = blockIdx.y * 64;
    const float* W = (n0 < 256) ? Wq : Wk;
    const int nloc = n0 & 255;
    const int tid = threadIdx.x;

    #pragma unroll
    for (int r = 0; r < 4; ++r) {
        int kl  = (tid >> 4) + r * 16;
        int nl4 = (tid & 15) * 4;
        f4 v = *(const f4*)&W[(size_t)(k0 + kl) * 256 + nloc + nl4];
        T[nl4 + 0][kl] = v.x;
        T[nl4 + 1][kl] = v.y;
        T[nl4 + 2][kl] = v.z;
        T[nl4 + 3][kl] = v.w;
    }
    __syncthreads();

    const int nl = tid >> 2;
    const int kq = (tid & 3) * 16;
    u4 o0, o1;
    #pragma unroll
    for (int j = 0; j < 4; ++j) {
        uint lo = rnd16(T[nl][kq + 2 * j]);
        uint hi = rnd16(T[nl][kq + 2 * j + 1]);
        ((uint*)&o0)[j] = (hi << 16) | lo;
    }
    #pragma unroll
    for (int j = 0; j < 4; ++j) {
        uint lo = rnd16(T[nl][kq + 8 + 2 * j]);
        uint hi = rnd16(T[nl][kq + 8 + 2 * j + 1]);
        ((uint*)&o1)[j] = (hi << 16) | lo;
    }
    ushort* dst = Wt + (size_t)(n0 + nl) * 1024 + k0 + kq;
    *(u4*)dst = o0;
    *(u4*)(dst + 8) = o1;
}

// ---------------------------------------------------------------------------
// Kernel 1: MFMA projection.  sq/sk[m][n] = sum_k x[m][k] * Wt[n][k]
// mfma(A=Wt_tile, B=x_tile): D lane owns col m = lane&15, 4 consecutive n.
// ---------------------------------------------------------------------------
__global__ __launch_bounds__(256) void proj_mfma(
    const float* __restrict__ x,       // [4096][1024] f32
    const ushort* __restrict__ Wt,     // [512][1024] bf16 bits
    ushort* __restrict__ sqb,          // [4096][256] bf16 bits
    ushort* __restrict__ skb)          // [4096][256] bf16 bits
{
    const int tid = threadIdx.x;
    const int l   = tid & 63;
    const int w   = __builtin_amdgcn_readfirstlane(tid) >> 6;  // 0..3
    const int cl  = l & 15;
    const int g4  = l >> 4;
    const int m0  = (blockIdx.x * 4 + w) * 16;   // m-tile
    const int n0  = blockIdx.y * 64;             // n-block (64 wide)

    f4 acc0 = {0,0,0,0}, acc1 = {0,0,0,0}, acc2 = {0,0,0,0}, acc3 = {0,0,0,0};

    const float*  xrow = x + (size_t)(m0 + cl) * 1024;
    const ushort* wbase = Wt + (size_t)(n0 + cl) * 1024;

    for (int ks = 0; ks < 32; ++ks) {
        const int k = ks * 32 + g4 * 8;
        f4 xa = *(const f4*)&xrow[k];
        f4 xb2 = *(const f4*)&xrow[k + 4];
        v8cast bf;
        ((uint*)&bf.u)[0] = (rnd16(xa.y) << 16) | rnd16(xa.x);
        ((uint*)&bf.u)[1] = (rnd16(xa.w) << 16) | rnd16(xa.z);
        ((uint*)&bf.u)[2] = (rnd16(xb2.y) << 16) | rnd16(xb2.x);
        ((uint*)&bf.u)[3] = (rnd16(xb2.w) << 16) | rnd16(xb2.z);
        s8v a0 = *(const s8v*)(wbase + 0 * 16 * 1024 + k);
        s8v a1 = *(const s8v*)(wbase + 1 * 16 * 1024 + k);
        s8v a2 = *(const s8v*)(wbase + 2 * 16 * 1024 + k);
        s8v a3 = *(const s8v*)(wbase + 3 * 16 * 1024 + k);
        acc0 = __builtin_amdgcn_mfma_f32_16x16x32_bf16(a0, bf.s, acc0, 0, 0, 0);
        acc1 = __builtin_amdgcn_mfma_f32_16x16x32_bf16(a1, bf.s, acc1, 0, 0, 0);
        acc2 = __builtin_amdgcn_mfma_f32_16x16x32_bf16(a2, bf.s, acc2, 0, 0, 0);
        acc3 = __builtin_amdgcn_mfma_f32_16x16x32_bf16(a3, bf.s, acc3, 0, 0, 0);
    }

    const int m = m0 + cl;
    const int nbase = n0 + g4 * 4;
    ushort* obase = (n0 < 256) ? (sqb + (size_t)m * 256 + nbase)
                               : (skb + (size_t)m * 256 + (nbase - 256));
    f4 accs[4] = {acc0, acc1, acc2, acc3};
    #pragma unroll
    for (int t = 0; t < 4; ++t) {
        u2 pk;
        pk.x = (rnd16(accs[t][1]) << 16) | rnd16(accs[t][0]);
        pk.y = (rnd16(accs[t][3]) << 16) | rnd16(accs[t][2]);
        *(u2*)(obase + t * 16) = pk;
    }
}

// ---------------------------------------------------------------------------
// Kernel 2: MFMA scores + mask + gumbel + softmax (swapped operands).
// NOW 1024-thread blocks (16 waves) per balanced strip-pair:
//  - one resident block fills a CU to 16 waves (R10 was dispatch-limited to
//    ~8: one 512-thr block/CU) -> 2x latency-hiding partners
//  - each wave owns <=8 tiles -> p[4][2] = 16 VGPRs (was 32), target VGPR
//    <=64 for the 8-waves/SIMD cap
//  - adjacent tile pairs (jt=2w+32it, +1) computed serially (keeps 128B-line
//    sharing, halves peak in-flight load regs)
// ---------------------------------------------------------------------------
__global__ __launch_bounds__(1024) void score_mfma(
    const ushort* __restrict__ sqb,     // [4096][256] bf16 bits
    const ushort* __restrict__ skb,     // [4096][256] bf16 bits
    const float*  __restrict__ gumbel,  // [B,H,T,T] f32
    const int*    __restrict__ mask,    // [H,T,T] int32 bool
    float* __restrict__ out)            // [B,H,T,T] f32
{
    const int tid = threadIdx.x;
    const int l   = tid & 63;
    const int w   = __builtin_amdgcn_readfirstlane(tid) >> 6;  // wave id 0..15
    const int bh  = blockIdx.x & 15;
    const int sp  = blockIdx.x >> 4;     // 0..63
    const int h   = bh & (HH - 1);
    const int b   = bh >> 3;
    const int cl  = l & 15;              // C col -> output row i offset
    const int g4  = l >> 4;              // 0..3  -> j sub-block
    const float RS = 0.17677669529663687f;  // 1/sqrt(RD)

    __shared__ float sums_lds[16][16];

    const ushort* sqbase = sqb + ((size_t)b * TT) * 256 + h * RDIM + g4 * 8;
    const ushort* skbase = skb + ((size_t)b * TT) * 256 + h * RDIM + g4 * 8;
    const float*  gb = gumbel + (size_t)bh * TT * TT;
    const int*    mb = mask + (size_t)h * TT * TT;
    float*        ob = out + (size_t)bh * TT * TT;

    #pragma unroll 1
    for (int half = 0; half < 2; ++half) {
        const int s      = half ? (127 - sp) : sp;
        const int i0     = s * 16;
        const int ntiles = s + 1;        // live 16-col tiles (max 128)
        const int zstart = ntiles * 16;
        const int i      = i0 + cl;      // this lane's output row

        // B fragment (sq row i): strip-invariant
        s8v bfrag = *(const s8v*)(sqbase + (size_t)i * 256);

        const float* grow = gb + (size_t)i * TT;
        const int*   mrow = mb + (size_t)i * TT;
        float*       orow = ob + (size_t)i * TT;

        // ---- pass 1: MFMA + exp, pack bf16, accumulate row sum ----
        float sum = 0.f;
        u2 p[4][2];
        #pragma unroll
        for (int it = 0; it < 4; ++it) {
            const int jt0 = 2 * w + it * 32;   // wave-uniform pair base
            #pragma unroll
            for (int u = 0; u < 2; ++u) {
                const int jt = jt0 + u;
                if (jt < ntiles) {
                    // A fragment (sk row j): row = jt*16 + (lane&15)
                    s8v afrag = *(const s8v*)(skbase + (size_t)(jt * 16 + cl) * 256);
                    f4 z = {0.f, 0.f, 0.f, 0.f};
                    f4 c = __builtin_amdgcn_mfma_f32_16x16x32_bf16(
                               afrag, bfrag, z, 0, 0, 0);
                    const int jb = jt * 16 + g4 * 4;   // 4 consecutive cols
                    f4 gv = *(const f4*)&grow[jb];
                    i4 mv = *(const i4*)&mrow[jb];
                    float e0 = (jb + 0 > i || mv.x) ? 0.f : __expf(fmaf(c[0], RS, gv.x));
                    float e1 = (jb + 1 > i || mv.y) ? 0.f : __expf(fmaf(c[1], RS, gv.y));
                    float e2 = (jb + 2 > i || mv.z) ? 0.f : __expf(fmaf(c[2], RS, gv.z));
                    float e3 = (jb + 3 > i || mv.w) ? 0.f : __expf(fmaf(c[3], RS, gv.w));
                    sum += (e0 + e1) + (e2 + e3);
                    p[it][u].x = (rnd16(e1) << 16) | rnd16(e0);
                    p[it][u].y = (rnd16(e3) << 16) | rnd16(e2);
                }
            }
        }

        // ---- row-sum reduce: across g4 groups, then across 16 waves ----
        sum += __shfl_xor(sum, 16);
        sum += __shfl_xor(sum, 32);
        if (l < 16) sums_lds[w][l] = sum;
        __syncthreads();
        float t = 0.f;
        #pragma unroll
        for (int ww = 0; ww < 16; ++ww) t += sums_lds[ww][cl];
        const float rinv = 1.0f / t;     // diagonal always live -> t > 0
        __syncthreads();                 // LDS reused by next half

        // ---- pass 2: unpack + scale + store (plain cached stores) ----
        #pragma unroll
        for (int it = 0; it < 4; ++it) {
            const int jt0 = 2 * w + it * 32;
            #pragma unroll
            for (int u = 0; u < 2; ++u) {
                const int jt = jt0 + u;
                if (jt < ntiles) {
                    const int jb = jt * 16 + g4 * 4;
                    f4 v;
                    v.x = __uint_as_float(p[it][u].x << 16) * rinv;
                    v.y = __uint_as_float(p[it][u].x & 0xffff0000u) * rinv;
                    v.z = __uint_as_float(p[it][u].y << 16) * rinv;
                    v.w = __uint_as_float(p[it][u].y & 0xffff0000u) * rinv;
                    *(f4*)&orow[jb] = v;
                }
            }
        }

        // ---- zero-fill cols beyond the causal frontier ----
        for (int r = 0; r < 16; ++r) {
            for (int cz = zstart + tid * 4; cz < TT; cz += 1024 * 4) {
                f4 zz = {0.f, 0.f, 0.f, 0.f};
                *(f4*)&ob[(size_t)(i0 + r) * TT + cz] = zz;
            }
        }
    }
}

extern "C" void kernel_launch(void* const* d_in, const int* in_sizes, int n_in,
                              void* d_out, int out_size, void* d_ws, size_t ws_size,
                              hipStream_t stream) {
    const float* x      = (const float*)d_in[0];
    const int*   bmask  = (const int*)d_in[1];   // bool -> int32 per harness
    const float* gumbel = (const float*)d_in[2];
    const float* Wq     = (const float*)d_in[3];
    const float* Wk     = (const float*)d_in[4];
    float* out = (float*)d_out;

    ushort* sqb = (ushort*)d_ws;                       // 4096*256 bf16 = 2 MB
    ushort* skb = sqb + (size_t)4096 * 256;            // 2 MB
    ushort* Wt  = skb + (size_t)4096 * 256;            // 512*1024 bf16 = 1 MB

    wt_prep<<<dim3(16, 8), 256, 0, stream>>>(Wq, Wk, Wt);
    proj_mfma<<<dim3(64, 8), 256, 0, stream>>>(x, Wt, sqb, skb);

    // 16 bh x 64 balanced strip-pairs, 1024 thr (16 waves) each
    score_mfma<<<1024, 1024, 0, stream>>>(sqb, skb, gumbel, bmask, out);
}